// Round 1
// baseline (160.055 us; speedup 1.0000x reference)
//
#include <hip/hip_runtime.h>
#include <hip/hip_bf16.h>

namespace {

constexpr int T_DIM = 16384;   // number of tiles
constexpr int TILE_K = 64;     // S0
constexpr int TILE_J = 64;     // S1
constexpr int TILES_PER_BLOCK = 8;

typedef __attribute__((ext_vector_type(8))) short bf16x8;
typedef __attribute__((ext_vector_type(4))) float f32x4;

__device__ inline short f2bf(float f) {
    union { __hip_bfloat16 h; short s; } u;
    u.h = __float2bfloat16(f);
    return u.s;
}

__device__ inline bf16x8 load_cvt8(const float* __restrict__ src) {
    f32x4 v0 = *reinterpret_cast<const f32x4*>(src);
    f32x4 v1 = *reinterpret_cast<const f32x4*>(src + 4);
    bf16x8 r;
    r[0] = f2bf(v0[0]); r[1] = f2bf(v0[1]); r[2] = f2bf(v0[2]); r[3] = f2bf(v0[3]);
    r[4] = f2bf(v1[0]); r[5] = f2bf(v1[1]); r[6] = f2bf(v1[2]); r[7] = f2bf(v1[3]);
    return r;
}

} // namespace

// 4 waves per block; wave w owns output rows [32w, 32w+32).
// No LDS, no barriers: each wave reads the W1 tile itself (L1 absorbs the 4x).
__global__ __launch_bounds__(256, 4) void fgbn_kernel(
    const float* __restrict__ x,
    const float* __restrict__ W1,
    const float* __restrict__ b1,
    const float* __restrict__ W2,
    const float* __restrict__ b2,
    float* __restrict__ out)
{
    const int lane = threadIdx.x & 63;
    const int wave = threadIdx.x >> 6;
    const int l15  = lane & 15;
    const int l4   = lane >> 4;

    // A fragments from x: A[row=lane&15][k=8*(lane>>4)+e]
    bf16x8 afrag[2][2];   // [rf][ks]
    #pragma unroll
    for (int rf = 0; rf < 2; ++rf) {
        const int row = wave * 32 + rf * 16 + l15;
        #pragma unroll
        for (int ks = 0; ks < 2; ++ks)
            afrag[rf][ks] = load_cvt8(x + row * TILE_K + ks * 32 + l4 * 8);
    }

    const int t0 = blockIdx.x * TILES_PER_BLOCK;

    for (int ti = 0; ti < TILES_PER_BLOCK; ++ti) {
        const int t = t0 + ti;
        const float* __restrict__ w1t = W1 + (size_t)t * (TILE_J * TILE_K);

        // B fragments: B[k=8*(lane>>4)+e][col=lane&15] = W1t[j][s]
        bf16x8 bfrag[4][2];   // [nf][ks]
        #pragma unroll
        for (int nf = 0; nf < 4; ++nf) {
            const int j = nf * 16 + l15;
            #pragma unroll
            for (int ks = 0; ks < 2; ++ks)
                bfrag[nf][ks] = load_cvt8(w1t + j * TILE_K + ks * 32 + l4 * 8);
        }

        // Per-tile bias / W2 values for the j indices this lane touches.
        float b1v[4], w2v[4];
        #pragma unroll
        for (int nf = 0; nf < 4; ++nf) {
            b1v[nf] = b1[t * TILE_J + nf * 16 + l15];
            w2v[nf] = W2[t * TILE_J + nf * 16 + l15];
        }
        const float b2t = b2[t];

        f32x4 acc[2][4];   // [rf][nf]
        #pragma unroll
        for (int rf = 0; rf < 2; ++rf)
            #pragma unroll
            for (int nf = 0; nf < 4; ++nf)
                acc[rf][nf] = (f32x4){0.f, 0.f, 0.f, 0.f};

        #pragma unroll
        for (int ks = 0; ks < 2; ++ks)
            #pragma unroll
            for (int rf = 0; rf < 2; ++rf)
                #pragma unroll
                for (int nf = 0; nf < 4; ++nf)
                    acc[rf][nf] = __builtin_amdgcn_mfma_f32_16x16x32_bf16(
                        afrag[rf][ks], bfrag[nf][ks], acc[rf][nf], 0, 0, 0);

        // Stage 2: y[b,t] = 2*(sum_j relu(h+b1)*W2 + b2).
        // D layout: row=(lane>>4)*4+r (b), col=lane&15 (j) -> reduce over the
        // 16-lane group with shfl_xor 1/2/4/8.
        #pragma unroll
        for (int rf = 0; rf < 2; ++rf) {
            #pragma unroll
            for (int r = 0; r < 4; ++r) {
                float s = 0.f;
                #pragma unroll
                for (int nf = 0; nf < 4; ++nf) {
                    float p = fmaxf(acc[rf][nf][r] + b1v[nf], 0.f);
                    s = fmaf(p, w2v[nf], s);
                }
                s += __shfl_xor(s, 1);
                s += __shfl_xor(s, 2);
                s += __shfl_xor(s, 4);
                s += __shfl_xor(s, 8);
                if (l15 == 0) {
                    const int brow = wave * 32 + rf * 16 + l4 * 4 + r;
                    out[(size_t)brow * T_DIM + t] = 2.f * (s + b2t);
                }
            }
        }
    }
}

extern "C" void kernel_launch(void* const* d_in, const int* in_sizes, int n_in,
                              void* d_out, int out_size, void* d_ws, size_t ws_size,
                              hipStream_t stream) {
    const float* x  = (const float*)d_in[0];
    const float* W1 = (const float*)d_in[1];
    const float* b1 = (const float*)d_in[2];
    const float* W2 = (const float*)d_in[3];
    const float* b2 = (const float*)d_in[4];
    float* out = (float*)d_out;

    dim3 grid(T_DIM / TILES_PER_BLOCK);
    dim3 block(256);
    hipLaunchKernelGGL(fgbn_kernel, grid, block, 0, stream,
                       x, W1, b1, W2, b2, out);
}

// Round 2
// 58.311 us; speedup vs baseline: 2.7448x; 2.7448x over previous
//
#include <hip/hip_runtime.h>
#include <hip/hip_bf16.h>

namespace {

constexpr int T_DIM = 16384;   // number of tiles
constexpr int NT    = 16;      // tiles per block -> grid = 1024
constexpr int NCHUNK = 1024;   // 16-B chunks per 64x64 f32 tile (16 KB)

typedef __attribute__((ext_vector_type(8))) short bf16x8;
typedef __attribute__((ext_vector_type(4))) float f32x4;

__device__ inline short f2bf(float f) {
    union { __hip_bfloat16 h; short s; } u;
    u.h = __float2bfloat16(f);
    return u.s;
}

} // namespace

// 4 waves / 256 threads; wave w owns output rows [32w, 32w+32).
// W1 tile staged once per block via async global_load_lds (16B), double-buffered.
// Swizzle (rule: both-sides-or-neither): LDS dest linear, global SOURCE chunk
// pre-swizzled g = c ^ ((c>>4)&7); reads apply the same XOR -> conflict-free.
__global__ __launch_bounds__(256, 4) void fgbn_kernel(
    const float* __restrict__ x,
    const float* __restrict__ W1,
    const float* __restrict__ b1,
    const float* __restrict__ W2,
    const float* __restrict__ b2,
    float* __restrict__ out)
{
    __shared__ float lds[2][NCHUNK * 4];   // 2 x 16 KB

    const int tid  = threadIdx.x;
    const int lane = tid & 63;
    const int wave = tid >> 6;
    const int l15  = lane & 15;
    const int l4   = lane >> 4;

    // A fragments from x: A[row=lane&15][k=8*(lane>>4)+e]
    bf16x8 afrag[2][2];   // [rf][ks]
    #pragma unroll
    for (int rf = 0; rf < 2; ++rf) {
        const int row = wave * 32 + rf * 16 + l15;
        #pragma unroll
        for (int ks = 0; ks < 2; ++ks) {
            const float* src = x + row * 64 + ks * 32 + l4 * 8;
            f32x4 v0 = *reinterpret_cast<const f32x4*>(src);
            f32x4 v1 = *reinterpret_cast<const f32x4*>(src + 4);
            bf16x8 r;
            r[0] = f2bf(v0[0]); r[1] = f2bf(v0[1]); r[2] = f2bf(v0[2]); r[3] = f2bf(v0[3]);
            r[4] = f2bf(v1[0]); r[5] = f2bf(v1[1]); r[6] = f2bf(v1[2]); r[7] = f2bf(v1[3]);
            afrag[rf][ks] = r;
        }
    }

    const int t0 = blockIdx.x * NT;

    // Async stage of one 16 KB W1 tile into lds[buf]; 4 x 1KB per wave.
    auto stage = [&](int buf, int t) {
        const char* w1t = (const char*)W1 + (size_t)t * 16384;
        #pragma unroll
        for (int it = 0; it < 4; ++it) {
            const int c = wave * 256 + it * 64 + lane;   // linear LDS chunk
            const int g = c ^ ((c >> 4) & 7);            // pre-swizzled global chunk
            __builtin_amdgcn_global_load_lds(
                (const __attribute__((address_space(1))) unsigned int*)(w1t + (size_t)g * 16),
                (__attribute__((address_space(3))) unsigned int*)&lds[buf][c * 4],
                16, 0, 0);
        }
    };

    // Prologue: tile-0 stage + per-tile vectors.
    float b1v[4], w2v[4];
    #pragma unroll
    for (int nf = 0; nf < 4; ++nf) {
        b1v[nf] = b1[t0 * 64 + nf * 16 + l15];
        w2v[nf] = W2[t0 * 64 + nf * 16 + l15];
    }
    float b2v = b2[t0];

    stage(0, t0);
    __syncthreads();

    f32x4 outv[2] = {{0.f,0.f,0.f,0.f},{0.f,0.f,0.f,0.f}};   // [rf][r]

    for (int ti = 0; ti < NT; ++ti) {
        const int t = t0 + ti;

        // Prefetch next tile (async LDS DMA + reg loads) before compute.
        float b1n[4], w2n[4], b2n = 0.f;
        if (ti + 1 < NT) {
            stage((ti + 1) & 1, t + 1);
            #pragma unroll
            for (int nf = 0; nf < 4; ++nf) {
                b1n[nf] = b1[(t + 1) * 64 + nf * 16 + l15];
                w2n[nf] = W2[(t + 1) * 64 + nf * 16 + l15];
            }
            b2n = b2[t + 1];
        }

        // Compute from lds[ti&1]: B[k][col=l15] = W1t[j=col][k].
        const float* lbuf = lds[ti & 1];
        f32x4 acc[2][4];
        #pragma unroll
        for (int rf = 0; rf < 2; ++rf)
            #pragma unroll
            for (int nf = 0; nf < 4; ++nf)
                acc[rf][nf] = (f32x4){0.f, 0.f, 0.f, 0.f};

        #pragma unroll
        for (int nf = 0; nf < 4; ++nf) {
            const int j = nf * 16 + l15;
            const int sw = j & 7;
            bf16x8 bks[2];
            #pragma unroll
            for (int ks = 0; ks < 2; ++ks) {
                const int c0 = j * 16 + ks * 8 + l4 * 2;
                f32x4 v0 = *reinterpret_cast<const f32x4*>(&lbuf[(c0 ^ sw) * 4]);
                f32x4 v1 = *reinterpret_cast<const f32x4*>(&lbuf[((c0 + 1) ^ sw) * 4]);
                bf16x8 r;
                r[0] = f2bf(v0[0]); r[1] = f2bf(v0[1]); r[2] = f2bf(v0[2]); r[3] = f2bf(v0[3]);
                r[4] = f2bf(v1[0]); r[5] = f2bf(v1[1]); r[6] = f2bf(v1[2]); r[7] = f2bf(v1[3]);
                bks[ks] = r;
            }
            #pragma unroll
            for (int ks = 0; ks < 2; ++ks)
                #pragma unroll
                for (int rf = 0; rf < 2; ++rf)
                    acc[rf][nf] = __builtin_amdgcn_mfma_f32_16x16x32_bf16(
                        afrag[rf][ks], bks[ks], acc[rf][nf], 0, 0, 0);
        }

        // Stage 2: y[b,t] = 2*(sum_j relu(h+b1)*W2 + b2); butterfly over the
        // 16-lane group leaves the sum in ALL lanes; lane l15==ti keeps tile ti.
        #pragma unroll
        for (int rf = 0; rf < 2; ++rf) {
            #pragma unroll
            for (int r = 0; r < 4; ++r) {
                float s = 0.f;
                #pragma unroll
                for (int nf = 0; nf < 4; ++nf) {
                    float p = fmaxf(acc[rf][nf][r] + b1v[nf], 0.f);
                    s = fmaf(p, w2v[nf], s);
                }
                s += __shfl_xor(s, 1);
                s += __shfl_xor(s, 2);
                s += __shfl_xor(s, 4);
                s += __shfl_xor(s, 8);
                const float v = 2.f * (s + b2v);
                outv[rf][r] = (l15 == ti) ? v : outv[rf][r];
            }
        }

        if (ti + 1 < NT) {
            #pragma unroll
            for (int nf = 0; nf < 4; ++nf) { b1v[nf] = b1n[nf]; w2v[nf] = w2n[nf]; }
            b2v = b2n;
        }
        __syncthreads();   // drains stage DMA (vmcnt) + guards buffer reuse
    }

    // Coalesced epilogue: 16 lanes cover t0..t0+15 -> full 64B lines.
    #pragma unroll
    for (int rf = 0; rf < 2; ++rf)
        #pragma unroll
        for (int r = 0; r < 4; ++r) {
            const int brow = wave * 32 + rf * 16 + l4 * 4 + r;
            out[(size_t)brow * T_DIM + t0 + l15] = outv[rf][r];
        }
}

extern "C" void kernel_launch(void* const* d_in, const int* in_sizes, int n_in,
                              void* d_out, int out_size, void* d_ws, size_t ws_size,
                              hipStream_t stream) {
    const float* x  = (const float*)d_in[0];
    const float* W1 = (const float*)d_in[1];
    const float* b1 = (const float*)d_in[2];
    const float* W2 = (const float*)d_in[3];
    const float* b2 = (const float*)d_in[4];
    float* out = (float*)d_out;

    dim3 grid(T_DIM / NT);
    dim3 block(256);
    hipLaunchKernelGGL(fgbn_kernel, grid, block, 0, stream,
                       x, W1, b1, W2, b2, out);
}